// Round 1
// 2209.304 us; speedup vs baseline: 1.4529x; 1.4529x over previous
//
#include <hip/hip_runtime.h>
#include <cstddef>

#define DEV static __device__ __forceinline__

constexpr int B_TOTAL = 32768;
constexpr int ROWS = 64;              // batch rows per block (lane = row)
constexpr int NBLK = B_TOTAL / ROWS;  // 512 blocks; each does q-phase then p-phase

// Padded transposed-weight layout per tower (floats).
// k' = unit*4 + gate (i,f,g,o) so a unit's 4 gate weights for one j are ONE float4.
// Layer0: rows 0..51 = x (j<50 real, 50..51 zero), rows 52..79 = h (jh<25 real) x 100 cols
// Layer1: rows 0..27 = x (j<25), rows 28..39 = h (jh<10) x 40 cols
// Layer2: rows 0..11 = x (j<10), rows 12..15 = h (jh<4)  x 16 cols
constexpr int TW1_OFF = 8000, TW2_OFF = 9600;
constexpr int BP0_OFF = 9856, BP1_OFF = 9956, BP2_OFF = 9996;
constexpr int TOW_FLOATS = 10016;                 // padded stride (16B aligned)
constexpr int HQ_OFF = 2 * TOW_FLOATS;            // 20032
constexpr int HP_OFF = HQ_OFF + B_TOTAL * 4;

DEV float fexp2(float x) { return __builtin_amdgcn_exp2f(x); }
DEV float frcp(float x) { return __builtin_amdgcn_rcpf(x); }
DEV float fsig(float x) { return frcp(1.0f + fexp2(-1.4426950408889634f * x)); }
DEV float ftanh_(float x) { return 2.0f * frcp(1.0f + fexp2(-2.8853900817779268f * x)) - 1.0f; }

// ---------------- prep: transpose + gate-interleave weights (zero-padded K) ---
__global__ __launch_bounds__(256) void prep_weights(
    const float* __restrict__ qWih0, const float* __restrict__ qWhh0, const float* __restrict__ qb0,
    const float* __restrict__ qWih1, const float* __restrict__ qWhh1, const float* __restrict__ qb1,
    const float* __restrict__ qWih2, const float* __restrict__ qWhh2, const float* __restrict__ qb2,
    const float* __restrict__ pWih0, const float* __restrict__ pWhh0, const float* __restrict__ pb0,
    const float* __restrict__ pWih1, const float* __restrict__ pWhh1, const float* __restrict__ pb1,
    const float* __restrict__ pWih2, const float* __restrict__ pWhh2, const float* __restrict__ pb2,
    float* __restrict__ ws) {
  const bool isp = (blockIdx.x == 1);
  const float* Wih0 = isp ? pWih0 : qWih0; const float* Whh0 = isp ? pWhh0 : qWhh0;
  const float* b0   = isp ? pb0   : qb0;
  const float* Wih1 = isp ? pWih1 : qWih1; const float* Whh1 = isp ? pWhh1 : qWhh1;
  const float* b1   = isp ? pb1   : qb1;
  const float* Wih2 = isp ? pWih2 : qWih2; const float* Whh2 = isp ? pWhh2 : qWhh2;
  const float* b2   = isp ? pb2   : qb2;
  float* out = ws + (isp ? TOW_FLOATS : 0);

  for (int e = threadIdx.x; e < TOW_FLOATS; e += 256) {
    float v = 0.0f;
    if (e < TW1_OFF) {                 // layer0: [80][100]
      const int i = e, j = i / 100, k = i % 100, u = k >> 2, gt = k & 3;
      const int rr = gt * 25 + u;
      if (j < 52) { if (j < 50) v = Wih0[rr * 50 + j]; }
      else        { const int jh = j - 52; if (jh < 25) v = Whh0[rr * 25 + jh]; }
    } else if (e < TW2_OFF) {          // layer1: [40][40]
      const int i = e - TW1_OFF, j = i / 40, k = i % 40, u = k >> 2, gt = k & 3;
      const int rr = gt * 10 + u;
      if (j < 28) { if (j < 25) v = Wih1[rr * 25 + j]; }
      else        { const int jh = j - 28; if (jh < 10) v = Whh1[rr * 10 + jh]; }
    } else if (e < BP0_OFF) {          // layer2: [16][16]
      const int i = e - TW2_OFF, j = i / 16, k = i % 16, u = k >> 2, gt = k & 3;
      const int rr = gt * 4 + u;
      if (j < 12) { if (j < 10) v = Wih2[rr * 10 + j]; }
      else        v = Whh2[rr * 4 + (j - 12)];
    } else if (e < BP1_OFF) {
      const int k = e - BP0_OFF, u = k >> 2, gt = k & 3; v = b0[gt * 25 + u];
    } else if (e < BP2_OFF) {
      const int k = e - BP1_OFF, u = k >> 2, gt = k & 3; v = b1[gt * 10 + u];
    } else if (e < BP2_OFF + 16) {
      const int k = e - BP2_OFF, u = k >> 2, gt = k & 3; v = b2[gt * 4 + u];
    }
    out[e] = v;
  }
}

// --------------- one LSTM layer step for NU units of this wave ---------------
// 4-j blocked: x-part XG float4 groups, h-part HG groups. N4 = N/4 (float4 cols).
// tw rows: [0,4*XG) = x (zero-padded), [4*XG, 4*XG+4*HG) = h (zero-padded).
template <int XG, int HG, int N4, int NU>
DEV void layer_fw(const float* __restrict__ tw, const float* __restrict__ bp,
                  const float* xin, const int xstr,
                  const float* hin, const int hstr,
                  const int u0, float* __restrict__ c, float* __restrict__ hout,
                  const int r) {
  float g[4 * NU];
#pragma unroll
  for (int u = 0; u < NU; ++u)
#pragma unroll
    for (int k = 0; k < 4; ++k) g[4 * u + k] = bp[4 * (u0 + u) + k];

  const float4* __restrict__ tw4 = reinterpret_cast<const float4*>(tw);
  for (int gi = 0; gi < XG; ++gi) {
    const float4 xv = *reinterpret_cast<const float4*>(xin + r * xstr + 4 * gi);
#pragma unroll
    for (int jj = 0; jj < 4; ++jj) {
      const float v = (jj == 0) ? xv.x : (jj == 1) ? xv.y : (jj == 2) ? xv.z : xv.w;
      const float4* __restrict__ wr = tw4 + (4 * gi + jj) * N4 + u0;
#pragma unroll
      for (int u = 0; u < NU; ++u) {
        const float4 wv = wr[u];
        g[4 * u + 0] = fmaf(wv.x, v, g[4 * u + 0]);
        g[4 * u + 1] = fmaf(wv.y, v, g[4 * u + 1]);
        g[4 * u + 2] = fmaf(wv.z, v, g[4 * u + 2]);
        g[4 * u + 3] = fmaf(wv.w, v, g[4 * u + 3]);
      }
    }
  }
  for (int gi = 0; gi < HG; ++gi) {
    const float4 hv = *reinterpret_cast<const float4*>(hin + r * hstr + 4 * gi);
#pragma unroll
    for (int jj = 0; jj < 4; ++jj) {
      const float v = (jj == 0) ? hv.x : (jj == 1) ? hv.y : (jj == 2) ? hv.z : hv.w;
      const float4* __restrict__ wr = tw4 + (4 * XG + 4 * gi + jj) * N4 + u0;
#pragma unroll
      for (int u = 0; u < NU; ++u) {
        const float4 wv = wr[u];
        g[4 * u + 0] = fmaf(wv.x, v, g[4 * u + 0]);
        g[4 * u + 1] = fmaf(wv.y, v, g[4 * u + 1]);
        g[4 * u + 2] = fmaf(wv.z, v, g[4 * u + 2]);
        g[4 * u + 3] = fmaf(wv.w, v, g[4 * u + 3]);
      }
    }
  }
#pragma unroll
  for (int u = 0; u < NU; ++u) {
    const float gi_ = fsig(g[4 * u + 0]);
    const float gf  = fsig(g[4 * u + 1]);
    const float gg  = ftanh_(g[4 * u + 2]);
    const float go  = fsig(g[4 * u + 3]);
    const float cn  = fmaf(gf, c[u], gi_ * gg);
    c[u] = cn;
    hout[u] = go * ftanh_(cn);
  }
}

// Layer2 replicated in every wave: all 4 units, recurrent h in registers.
DEV void layer2_fw(const float* __restrict__ tw, const float* __restrict__ bp,
                   const float* xin, const int xstr,
                   float* __restrict__ c, float* __restrict__ h, const int r) {
  float g[16];
#pragma unroll
  for (int k = 0; k < 16; ++k) g[k] = bp[k];
  const float4* __restrict__ tw4 = reinterpret_cast<const float4*>(tw);  // N4 = 4
  for (int gi = 0; gi < 3; ++gi) {
    const float4 xv = *reinterpret_cast<const float4*>(xin + r * xstr + 4 * gi);
#pragma unroll
    for (int jj = 0; jj < 4; ++jj) {
      const float v = (jj == 0) ? xv.x : (jj == 1) ? xv.y : (jj == 2) ? xv.z : xv.w;
      const float4* __restrict__ wr = tw4 + (4 * gi + jj) * 4;
#pragma unroll
      for (int u = 0; u < 4; ++u) {
        const float4 wv = wr[u];
        g[4 * u + 0] = fmaf(wv.x, v, g[4 * u + 0]);
        g[4 * u + 1] = fmaf(wv.y, v, g[4 * u + 1]);
        g[4 * u + 2] = fmaf(wv.z, v, g[4 * u + 2]);
        g[4 * u + 3] = fmaf(wv.w, v, g[4 * u + 3]);
      }
    }
  }
#pragma unroll
  for (int jj = 0; jj < 4; ++jj) {   // recurrent part from registers (read-all-before-write)
    const float v = h[jj];
    const float4* __restrict__ wr = tw4 + (12 + jj) * 4;
#pragma unroll
    for (int u = 0; u < 4; ++u) {
      const float4 wv = wr[u];
      g[4 * u + 0] = fmaf(wv.x, v, g[4 * u + 0]);
      g[4 * u + 1] = fmaf(wv.y, v, g[4 * u + 1]);
      g[4 * u + 2] = fmaf(wv.z, v, g[4 * u + 2]);
      g[4 * u + 3] = fmaf(wv.w, v, g[4 * u + 3]);
    }
  }
#pragma unroll
  for (int u = 0; u < 4; ++u) {
    const float gi_ = fsig(g[4 * u + 0]);
    const float gf  = fsig(g[4 * u + 1]);
    const float gg  = ftanh_(g[4 * u + 2]);
    const float go  = fsig(g[4 * u + 3]);
    const float cn  = fmaf(gf, c[u], gi_ * gg);
    c[u] = cn;
    h[u] = go * ftanh_(cn);
  }
}

// 512 blocks x 512 threads (8 waves). Each block: 64 rows through q tower
// (T=12) then p tower (T=50). Unit split 8-way; layer2 replicated.
// 2 barriers per timestep (double-buffered x/h0/h1; h2 in regs).
__global__ __launch_bounds__(512, 4) void lstm_towers(
    const float* __restrict__ q, const float* __restrict__ p,
    const float* __restrict__ wts, float* __restrict__ hq_out,
    float* __restrict__ hp_out) {
  __shared__ float xb[2][ROWS * 52];   // stride 52 (52r mod 32 spans banks)
  __shared__ float h0b[2][ROWS * 28];  // 25 units + 3 zero pad
  __shared__ float h1b[2][ROWS * 12];  // 10 units + 2 zero pad

  const int tid = threadIdx.x;
  const int r = tid & 63;
  const int wid = tid >> 6;  // 0..7
  const int row0 = blockIdx.x * ROWS;

  // wave-uniform unit offsets (readfirstlane -> SGPR, keeps weight loads scalar)
  const int u00 = __builtin_amdgcn_readfirstlane(wid ? (3 * wid + 1) : 0);  // {0,4,7,..,22}
  const int nu0 = wid ? 3 : 4;
  const int u01 = __builtin_amdgcn_readfirstlane((wid < 2) ? 2 * wid : wid + 2);  // {0,2,4..9}
  const int nu1 = (wid < 2) ? 2 : 1;

  // zero xb pad columns once (both buffers); never overwritten afterwards
  for (int i = tid; i < 2 * ROWS; i += 512) {
    const int b = i >> 6, rr = i & 63;
    xb[b][rr * 52 + 50] = 0.0f;
    xb[b][rr * 52 + 51] = 0.0f;
  }

#pragma unroll 1
  for (int phase = 0; phase < 2; ++phase) {
    const bool isp = (phase == 1);
    const float* __restrict__ x = isp ? p : q;
    const int T = isp ? 50 : 12;
    const float* __restrict__ tw = wts + (isp ? TOW_FLOATS : 0);
    float* __restrict__ hout_g = isp ? hp_out : hq_out;
    const float* __restrict__ tw0 = tw;            const float* __restrict__ bp0 = tw + BP0_OFF;
    const float* __restrict__ tw1 = tw + TW1_OFF;  const float* __restrict__ bp1 = tw + BP1_OFF;
    const float* __restrict__ tw2 = tw + TW2_OFF;  const float* __restrict__ bp2 = tw + BP2_OFF;

    __syncthreads();  // previous phase's LDS reads done before re-zero
    {                 // zero h-state buffers (both; covers pads)
      float* z0 = &h0b[0][0];
      for (int i = tid; i < 2 * ROWS * 28; i += 512) z0[i] = 0.0f;
      float* z1 = &h1b[0][0];
      for (int i = tid; i < 2 * ROWS * 12; i += 512) z1[i] = 0.0f;
    }
    // preload x_0 into xb[0]
    for (int i = tid; i < 1600; i += 512) {
      const int rr = i / 25, j2 = i % 25;
      const float2 v = *reinterpret_cast<const float2*>(
          x + ((size_t)(row0 + rr) * T) * 50 + 2 * j2);
      xb[0][rr * 52 + 2 * j2] = v.x;
      xb[0][rr * 52 + 2 * j2 + 1] = v.y;
    }
    float c0[4] = {}, c1[2] = {}, c2[4] = {};
    float h2r[4] = {0.0f, 0.0f, 0.0f, 0.0f};
    float h0n[4], h1n[2];
    __syncthreads();

    int s = 0;
#pragma unroll 1
    for (int t = 0; t < T; ++t) {
      // T14 async stage: issue x_{t+1} global loads now, LDS-write after bar1
      float2 xs0 = {0.f, 0.f}, xs1 = {0.f, 0.f}, xs2 = {0.f, 0.f}, xs3 = {0.f, 0.f};
      const bool more = (t + 1 < T);
      const int i0 = tid, i1 = tid + 512, i2 = tid + 1024, i3 = tid + 1536;
      if (more) {
        xs0 = *reinterpret_cast<const float2*>(x + ((size_t)(row0 + i0 / 25) * T + t + 1) * 50 + 2 * (i0 % 25));
        xs1 = *reinterpret_cast<const float2*>(x + ((size_t)(row0 + i1 / 25) * T + t + 1) * 50 + 2 * (i1 % 25));
        xs2 = *reinterpret_cast<const float2*>(x + ((size_t)(row0 + i2 / 25) * T + t + 1) * 50 + 2 * (i2 % 25));
        if (i3 < 1600)
          xs3 = *reinterpret_cast<const float2*>(x + ((size_t)(row0 + i3 / 25) * T + t + 1) * 50 + 2 * (i3 % 25));
      }
      // L0: read xb[s], h0b[s]; write h0b[s^1]
      if (wid == 0) layer_fw<13, 7, 25, 4>(tw0, bp0, xb[s], 52, h0b[s], 28, u00, c0, h0n, r);
      else          layer_fw<13, 7, 25, 3>(tw0, bp0, xb[s], 52, h0b[s], 28, u00, c0, h0n, r);
      {
        float* d = &h0b[s ^ 1][r * 28 + u00];
        d[0] = h0n[0]; d[1] = h0n[1]; d[2] = h0n[2];
        if (nu0 == 4) d[3] = h0n[3];
      }
      __syncthreads();  // bar1: h0_t visible
      if (more) {       // write staged x_{t+1} into xb[s^1]
        xb[s ^ 1][(i0 / 25) * 52 + 2 * (i0 % 25)] = xs0.x;
        xb[s ^ 1][(i0 / 25) * 52 + 2 * (i0 % 25) + 1] = xs0.y;
        xb[s ^ 1][(i1 / 25) * 52 + 2 * (i1 % 25)] = xs1.x;
        xb[s ^ 1][(i1 / 25) * 52 + 2 * (i1 % 25) + 1] = xs1.y;
        xb[s ^ 1][(i2 / 25) * 52 + 2 * (i2 % 25)] = xs2.x;
        xb[s ^ 1][(i2 / 25) * 52 + 2 * (i2 % 25) + 1] = xs2.y;
        if (i3 < 1600) {
          xb[s ^ 1][(i3 / 25) * 52 + 2 * (i3 % 25)] = xs3.x;
          xb[s ^ 1][(i3 / 25) * 52 + 2 * (i3 % 25) + 1] = xs3.y;
        }
      }
      // L1: read h0b[s^1], h1b[s]; write h1b[s^1]
      if (wid < 2) layer_fw<7, 3, 10, 2>(tw1, bp1, h0b[s ^ 1], 28, h1b[s], 12, u01, c1, h1n, r);
      else         layer_fw<7, 3, 10, 1>(tw1, bp1, h0b[s ^ 1], 28, h1b[s], 12, u01, c1, h1n, r);
      {
        float* d = &h1b[s ^ 1][r * 12 + u01];
        d[0] = h1n[0];
        if (nu1 == 2) d[1] = h1n[1];
      }
      __syncthreads();  // bar2: h1_t (and staged x) visible
      // L2: replicated, all-register state
      layer2_fw(tw2, bp2, h1b[s ^ 1], 12, c2, h2r, r);
      s ^= 1;
    }
    if (wid == 0) {
      reinterpret_cast<float4*>(hout_g)[row0 + r] =
          make_float4(h2r[0], h2r[1], h2r[2], h2r[3]);
    }
  }
}

// ---------------- head: softmax((hq*hp) @ fW^T + fb) -------------------------
__global__ __launch_bounds__(256) void combine_head(
    const float* __restrict__ hq, const float* __restrict__ hp,
    const float* __restrict__ fW, const float* __restrict__ fb,
    float* __restrict__ out) {
  const int b = blockIdx.x * blockDim.x + (int)threadIdx.x;
  if (b >= B_TOTAL) return;
  const float4 vq = reinterpret_cast<const float4*>(hq)[b];
  const float4 vp = reinterpret_cast<const float4*>(hp)[b];
  const float s0 = vq.x * vp.x, s1 = vq.y * vp.y, s2 = vq.z * vp.z, s3 = vq.w * vp.w;
  float l0 = fb[0], l1 = fb[1];
  l0 = fmaf(s0, fW[0], l0); l0 = fmaf(s1, fW[1], l0); l0 = fmaf(s2, fW[2], l0); l0 = fmaf(s3, fW[3], l0);
  l1 = fmaf(s0, fW[4], l1); l1 = fmaf(s1, fW[5], l1); l1 = fmaf(s2, fW[6], l1); l1 = fmaf(s3, fW[7], l1);
  const float m = fmaxf(l0, l1);
  const float e0 = fexp2(1.4426950408889634f * (l0 - m));
  const float e1 = fexp2(1.4426950408889634f * (l1 - m));
  const float inv = frcp(e0 + e1);
  reinterpret_cast<float2*>(out)[b] = make_float2(e0 * inv, e1 * inv);
}

extern "C" void kernel_launch(void* const* d_in, const int* in_sizes, int n_in,
                              void* d_out, int out_size, void* d_ws, size_t ws_size,
                              hipStream_t stream) {
  (void)in_sizes; (void)n_in; (void)out_size; (void)ws_size;
  const float* q = (const float*)d_in[0];
  const float* p = (const float*)d_in[1];
  float* ws = (float*)d_ws;

  prep_weights<<<2, 256, 0, stream>>>(
      (const float*)d_in[2], (const float*)d_in[3], (const float*)d_in[4],
      (const float*)d_in[5], (const float*)d_in[6], (const float*)d_in[7],
      (const float*)d_in[8], (const float*)d_in[9], (const float*)d_in[10],
      (const float*)d_in[11], (const float*)d_in[12], (const float*)d_in[13],
      (const float*)d_in[14], (const float*)d_in[15], (const float*)d_in[16],
      (const float*)d_in[17], (const float*)d_in[18], (const float*)d_in[19],
      ws);

  lstm_towers<<<NBLK, 512, 0, stream>>>(q, p, ws, ws + HQ_OFF, ws + HP_OFF);

  combine_head<<<B_TOTAL / 256, 256, 0, stream>>>(
      ws + HQ_OFF, ws + HP_OFF,
      (const float*)d_in[20], (const float*)d_in[21], (float*)d_out);
}

// Round 2
// 1359.549 us; speedup vs baseline: 2.3609x; 1.6250x over previous
//
#include <hip/hip_runtime.h>
#include <cstddef>

#define DEV static __device__ __forceinline__

constexpr int B_TOTAL = 32768;
constexpr int ROWS = 128;             // batch rows per block (2 per lane)
constexpr int NBLK = B_TOTAL / ROWS;  // 256 blocks = 1 per CU

// LDS weight layout per phase (floats), gate-interleaved columns k' = 4*unit+gate:
//   WL0 @0    : 78 rows x 100  (rows 0..49 = x(j), 50..77 = h(jh), jh>=25 zero)
//   WL1 @7800 : 40 rows x 40   (rows 0..27 = h0 incl 3 zero rows, 28..39 = h1 incl 2 zero)
//   WL2 @9400 : 16 rows x 16   (rows 0..11 = h1 incl 2 zero, 12..15 = h2)
constexpr int WL1_OFF = 7800, WL2_OFF = 9400, W_TOTAL = 9656;
constexpr int H0_STR = 28;   // 25 units + 3 zero pad (4*odd -> good quad spread)
constexpr int H1_STR = 12;   // 10 units + 2 zero pad
constexpr int HQ_OFF = 0;
constexpr int HP_OFF = B_TOTAL * 4;

DEV float fexp2(float x) { return __builtin_amdgcn_exp2f(x); }
DEV float frcp(float x) { return __builtin_amdgcn_rcpf(x); }
DEV float fsig(float x) { return frcp(1.0f + fexp2(-1.4426950408889634f * x)); }
DEV float ftanh_(float x) { return 2.0f * frcp(1.0f + fexp2(-2.8853900817779268f * x)) - 1.0f; }

DEV float elem4(const float4 v, const int jj) {
  return jj == 0 ? v.x : jj == 1 ? v.y : jj == 2 ? v.z : v.w;
}

// NU units x 4 gates x 2 rows of FMAs from one broadcast weight float4 row.
template <int NU>
DEV void gfma(float* __restrict__ g0, float* __restrict__ g1,
              const float4* __restrict__ w, const float va, const float vb) {
#pragma unroll
  for (int u = 0; u < NU; ++u) {
    const float4 wv = w[u];
    g0[4 * u + 0] = fmaf(wv.x, va, g0[4 * u + 0]);
    g0[4 * u + 1] = fmaf(wv.y, va, g0[4 * u + 1]);
    g0[4 * u + 2] = fmaf(wv.z, va, g0[4 * u + 2]);
    g0[4 * u + 3] = fmaf(wv.w, va, g0[4 * u + 3]);
    g1[4 * u + 0] = fmaf(wv.x, vb, g1[4 * u + 0]);
    g1[4 * u + 1] = fmaf(wv.y, vb, g1[4 * u + 1]);
    g1[4 * u + 2] = fmaf(wv.z, vb, g1[4 * u + 2]);
    g1[4 * u + 3] = fmaf(wv.w, vb, g1[4 * u + 3]);
  }
}

template <int NU>
DEV void activ(const float* __restrict__ g, float* __restrict__ c,
               float* __restrict__ hn) {
#pragma unroll
  for (int u = 0; u < NU; ++u) {
    const float gi_ = fsig(g[4 * u + 0]);
    const float gf  = fsig(g[4 * u + 1]);
    const float gg  = ftanh_(g[4 * u + 2]);
    const float go  = fsig(g[4 * u + 3]);
    const float cn  = fmaf(gf, c[u], gi_ * gg);
    c[u] = cn;
    hn[u] = go * ftanh_(cn);
  }
}

// Layer 0: x from global (2 rows/lane, float2-granular), h from LDS h0.
// c,hn layout: [row][4] (row b at +4).
template <int NU>
DEV void l0_fw(const float* __restrict__ wl, const float* __restrict__ bia,
               const float* __restrict__ xa, const float* __restrict__ xb,
               const float* h0, const int ra, const int rb, const int u0,
               float* __restrict__ c, float* __restrict__ hn) {
  float g0[4 * NU], g1[4 * NU];
#pragma unroll
  for (int k = 0; k < 4 * NU; ++k) { g0[k] = bia[k]; g1[k] = bia[k]; }

#pragma unroll 5
  for (int m = 0; m < 25; ++m) {
    const float2 a2 = *reinterpret_cast<const float2*>(xa + 2 * m);
    const float2 b2 = *reinterpret_cast<const float2*>(xb + 2 * m);
    const float4* w0 = reinterpret_cast<const float4*>(wl + (2 * m) * 100) + u0;
    const float4* w1 = reinterpret_cast<const float4*>(wl + (2 * m + 1) * 100) + u0;
    gfma<NU>(g0, g1, w0, a2.x, b2.x);
    gfma<NU>(g0, g1, w1, a2.y, b2.y);
  }
#pragma unroll
  for (int gi = 0; gi < 7; ++gi) {
    const float4 ha = *reinterpret_cast<const float4*>(h0 + ra * H0_STR + 4 * gi);
    const float4 hb = *reinterpret_cast<const float4*>(h0 + rb * H0_STR + 4 * gi);
#pragma unroll
    for (int jj = 0; jj < 4; ++jj) {
      const float4* w = reinterpret_cast<const float4*>(wl + (50 + 4 * gi + jj) * 100) + u0;
      gfma<NU>(g0, g1, w, elem4(ha, jj), elem4(hb, jj));
    }
  }
  activ<NU>(g0, c, hn);
  activ<NU>(g1, c + 4, hn + 4);
}

// Layer 1: x = h0 (LDS), h = h1[s] (LDS). c,hn layout: [row][2] (row b at +2).
template <int NU>
DEV void l1_fw(const float* __restrict__ wl, const float* __restrict__ bia,
               const float* h0, const float* h1, const int ra, const int rb,
               const int u0, float* __restrict__ c, float* __restrict__ hn) {
  float g0[4 * NU], g1[4 * NU];
#pragma unroll
  for (int k = 0; k < 4 * NU; ++k) { g0[k] = bia[k]; g1[k] = bia[k]; }
#pragma unroll
  for (int gi = 0; gi < 7; ++gi) {
    const float4 ha = *reinterpret_cast<const float4*>(h0 + ra * H0_STR + 4 * gi);
    const float4 hb = *reinterpret_cast<const float4*>(h0 + rb * H0_STR + 4 * gi);
#pragma unroll
    for (int jj = 0; jj < 4; ++jj) {
      const float4* w = reinterpret_cast<const float4*>(wl + (4 * gi + jj) * 40) + u0;
      gfma<NU>(g0, g1, w, elem4(ha, jj), elem4(hb, jj));
    }
  }
#pragma unroll
  for (int gi = 0; gi < 3; ++gi) {
    const float4 ha = *reinterpret_cast<const float4*>(h1 + ra * H1_STR + 4 * gi);
    const float4 hb = *reinterpret_cast<const float4*>(h1 + rb * H1_STR + 4 * gi);
#pragma unroll
    for (int jj = 0; jj < 4; ++jj) {
      const float4* w = reinterpret_cast<const float4*>(wl + (28 + 4 * gi + jj) * 40) + u0;
      gfma<NU>(g0, g1, w, elem4(ha, jj), elem4(hb, jj));
    }
  }
  activ<NU>(g0, c, hn);
  activ<NU>(g1, c + 2, hn + 2);
}

// Layer 2 (one wave, all 4 units, recurrent h in registers). c,h2: [row][4].
DEV void l2_fw(const float* __restrict__ wl, const float* __restrict__ bi2,
               const float* h1, const int ra, const int rb,
               float* __restrict__ c, float* __restrict__ h2) {
  float g0[16], g1[16];
#pragma unroll
  for (int k = 0; k < 16; ++k) { g0[k] = bi2[k]; g1[k] = bi2[k]; }
#pragma unroll
  for (int gi = 0; gi < 3; ++gi) {
    const float4 ha = *reinterpret_cast<const float4*>(h1 + ra * H1_STR + 4 * gi);
    const float4 hb = *reinterpret_cast<const float4*>(h1 + rb * H1_STR + 4 * gi);
#pragma unroll
    for (int jj = 0; jj < 4; ++jj) {
      const float4* w = reinterpret_cast<const float4*>(wl + (4 * gi + jj) * 16);
      gfma<4>(g0, g1, w, elem4(ha, jj), elem4(hb, jj));
    }
  }
#pragma unroll
  for (int jj = 0; jj < 4; ++jj) {  // recurrent part: reads all h2 before activ writes
    const float4* w = reinterpret_cast<const float4*>(wl + (12 + jj) * 16);
    gfma<4>(g0, g1, w, h2[jj], h2[4 + jj]);
  }
  activ<4>(g0, c, h2);
  activ<4>(g1, c + 4, h2 + 4);
}

// 256 blocks x 512 threads (8 waves, 2 waves/SIMD, 1 block/CU).
// Each block: 128 rows (lane r owns rows r and r+64) through q tower then p tower.
// Weights transposed into LDS once per phase; 3 barriers/step; layer2 solo on
// wave 7 overlaps next step's layer 0.
__global__ __launch_bounds__(512, 2) void lstm_towers(
    const float* __restrict__ q, const float* __restrict__ p,
    const float* __restrict__ qWih0, const float* __restrict__ qWhh0, const float* __restrict__ qb0,
    const float* __restrict__ qWih1, const float* __restrict__ qWhh1, const float* __restrict__ qb1,
    const float* __restrict__ qWih2, const float* __restrict__ qWhh2, const float* __restrict__ qb2,
    const float* __restrict__ pWih0, const float* __restrict__ pWhh0, const float* __restrict__ pb0,
    const float* __restrict__ pWih1, const float* __restrict__ pWhh1, const float* __restrict__ pb1,
    const float* __restrict__ pWih2, const float* __restrict__ pWhh2, const float* __restrict__ pb2,
    float* __restrict__ hq_out, float* __restrict__ hp_out) {
  __shared__ float wlds[W_TOTAL];      // 38624 B
  __shared__ float h0s[ROWS * H0_STR]; // 14336 B (single buffer)
  __shared__ float h1s[2 * ROWS * H1_STR]; // 12288 B (double buffer)

  const int tid = threadIdx.x;
  const int r = tid & 63;
  const int wid = tid >> 6;  // 0..7
  const int row0 = blockIdx.x * ROWS;
  const int ra = r, rb = r + 64;

  // unit splits: L0 {4,4,3,3,3,3,3,2}, L1 {2,2,1,1,1,1,1,1}; wave7 light -> owns L2
  const int u00 = __builtin_amdgcn_readfirstlane(
      wid < 2 ? 4 * wid : (wid < 7 ? 8 + 3 * (wid - 2) : 23));
  const int u01 = __builtin_amdgcn_readfirstlane(wid < 2 ? 2 * wid : wid + 2);

  const float* wl0 = wlds;
  const float* wl1 = wlds + WL1_OFF;
  const float* wl2 = wlds + WL2_OFF;

#pragma unroll 1
  for (int phase = 0; phase < 2; ++phase) {
    const bool isp = (phase == 1);
    const float* __restrict__ x = isp ? p : q;
    const int T = isp ? 50 : 12;
    const float* Wih0 = isp ? pWih0 : qWih0; const float* Whh0 = isp ? pWhh0 : qWhh0;
    const float* b0g  = isp ? pb0   : qb0;
    const float* Wih1 = isp ? pWih1 : qWih1; const float* Whh1 = isp ? pWhh1 : qWhh1;
    const float* b1g  = isp ? pb1   : qb1;
    const float* Wih2 = isp ? pWih2 : qWih2; const float* Whh2 = isp ? pWhh2 : qWhh2;
    const float* b2g  = isp ? pb2   : qb2;
    float* __restrict__ hout_g = isp ? hp_out : hq_out;

    __syncthreads();  // prior phase fully done with LDS before rewrite

    // ---- transpose + gate-interleave weights into LDS (zero-padded rows) ----
    for (int e = tid; e < W_TOTAL; e += 512) {
      float v = 0.0f;
      if (e < WL1_OFF) {
        const int j = e / 100, k = e % 100, u = k >> 2, gt = k & 3, rr = gt * 25 + u;
        if (j < 50) v = Wih0[rr * 50 + j];
        else { const int jh = j - 50; if (jh < 25) v = Whh0[rr * 25 + jh]; }
      } else if (e < WL2_OFF) {
        const int i = e - WL1_OFF, j = i / 40, k = i % 40, u = k >> 2, gt = k & 3;
        const int rr = gt * 10 + u;
        if (j < 25) v = Wih1[rr * 25 + j];
        else if (j >= 28) { const int jh = j - 28; if (jh < 10) v = Whh1[rr * 10 + jh]; }
      } else {
        const int i = e - WL2_OFF, j = i / 16, k = i % 16, u = k >> 2, gt = k & 3;
        const int rr = gt * 4 + u;
        if (j < 10) v = Wih2[rr * 10 + j];
        else if (j >= 12) v = Whh2[rr * 4 + (j - 12)];
      }
      wlds[e] = v;
    }
    for (int i = tid; i < ROWS * H0_STR; i += 512) h0s[i] = 0.0f;
    for (int i = tid; i < 2 * ROWS * H1_STR; i += 512) h1s[i] = 0.0f;

    // ---- biases into registers (t-invariant, uniform loads) ----
    float bia0[16], bia1[8], bi2[16];
#pragma unroll
    for (int u = 0; u < 4; ++u) {
      const int ui = (u00 + u < 25) ? u00 + u : 24;
#pragma unroll
      for (int gt = 0; gt < 4; ++gt) bia0[4 * u + gt] = b0g[gt * 25 + ui];
    }
#pragma unroll
    for (int u = 0; u < 2; ++u) {
      const int ui = (u01 + u < 10) ? u01 + u : 9;
#pragma unroll
      for (int gt = 0; gt < 4; ++gt) bia1[4 * u + gt] = b1g[gt * 10 + ui];
    }
    if (wid == 7) {
#pragma unroll
      for (int u = 0; u < 4; ++u)
#pragma unroll
        for (int gt = 0; gt < 4; ++gt) bi2[4 * u + gt] = b2g[gt * 4 + u];
    }

    float c0[8] = {}, hn0[8];
    float c1[4] = {}, hn1[4];
    float c2[8] = {}, h2r[8] = {};

    const float* xa = x + (size_t)(row0 + ra) * T * 50;
    const float* xb = x + (size_t)(row0 + rb) * T * 50;

    __syncthreads();  // weights + zeroed state visible

    int s = 0;
#pragma unroll 1
    for (int t = 0; t < T; ++t) {
      // ---- L0 (reads h0 = h0_{t-1}) ----
      if (wid < 2)      l0_fw<4>(wl0, bia0, xa, xb, h0s, ra, rb, u00, c0, hn0);
      else if (wid < 7) l0_fw<3>(wl0, bia0, xa, xb, h0s, ra, rb, u00, c0, hn0);
      else              l0_fw<2>(wl0, bia0, xa, xb, h0s, ra, rb, u00, c0, hn0);
      __syncthreads();  // bar1: all h0 reads done
      {
        float* da = &h0s[ra * H0_STR + u00];
        float* db = &h0s[rb * H0_STR + u00];
        if (wid < 2) {
          da[0] = hn0[0]; da[1] = hn0[1]; da[2] = hn0[2]; da[3] = hn0[3];
          db[0] = hn0[4]; db[1] = hn0[5]; db[2] = hn0[6]; db[3] = hn0[7];
        } else if (wid < 7) {
          da[0] = hn0[0]; da[1] = hn0[1]; da[2] = hn0[2];
          db[0] = hn0[4]; db[1] = hn0[5]; db[2] = hn0[6];
        } else {
          da[0] = hn0[0]; da[1] = hn0[1];
          db[0] = hn0[4]; db[1] = hn0[5];
        }
      }
      __syncthreads();  // bar2: h0_t visible
      // ---- L1 (reads h0_t and h1[s] = h1_{t-1}; writes h1[s^1]) ----
      const float* h1rd = h1s + s * (ROWS * H1_STR);
      float* h1wr = h1s + (s ^ 1) * (ROWS * H1_STR);
      if (wid < 2) l1_fw<2>(wl1, bia1, h0s, h1rd, ra, rb, u01, c1, hn1);
      else         l1_fw<1>(wl1, bia1, h0s, h1rd, ra, rb, u01, c1, hn1);
      {
        float* ea = &h1wr[ra * H1_STR + u01];
        float* eb = &h1wr[rb * H1_STR + u01];
        if (wid < 2) { ea[0] = hn1[0]; ea[1] = hn1[1]; eb[0] = hn1[2]; eb[1] = hn1[3]; }
        else         { ea[0] = hn1[0]; eb[0] = hn1[2]; }
      }
      __syncthreads();  // bar3: h1_t visible
      // ---- L2 solo on wave 7; overlaps other waves' next-step L0 ----
      if (wid == 7) l2_fw(wl2, bi2, h1wr, ra, rb, c2, h2r);
      s ^= 1;
      xa += 50; xb += 50;
    }
    if (wid == 7) {
      reinterpret_cast<float4*>(hout_g)[row0 + ra] =
          make_float4(h2r[0], h2r[1], h2r[2], h2r[3]);
      reinterpret_cast<float4*>(hout_g)[row0 + rb] =
          make_float4(h2r[4], h2r[5], h2r[6], h2r[7]);
    }
  }
}

// ---------------- head: softmax((hq*hp) @ fW^T + fb) -------------------------
__global__ __launch_bounds__(256) void combine_head(
    const float* __restrict__ hq, const float* __restrict__ hp,
    const float* __restrict__ fW, const float* __restrict__ fb,
    float* __restrict__ out) {
  const int b = blockIdx.x * blockDim.x + (int)threadIdx.x;
  if (b >= B_TOTAL) return;
  const float4 vq = reinterpret_cast<const float4*>(hq)[b];
  const float4 vp = reinterpret_cast<const float4*>(hp)[b];
  const float s0 = vq.x * vp.x, s1 = vq.y * vp.y, s2 = vq.z * vp.z, s3 = vq.w * vp.w;
  float l0 = fb[0], l1 = fb[1];
  l0 = fmaf(s0, fW[0], l0); l0 = fmaf(s1, fW[1], l0); l0 = fmaf(s2, fW[2], l0); l0 = fmaf(s3, fW[3], l0);
  l1 = fmaf(s0, fW[4], l1); l1 = fmaf(s1, fW[5], l1); l1 = fmaf(s2, fW[6], l1); l1 = fmaf(s3, fW[7], l1);
  const float m = fmaxf(l0, l1);
  const float e0 = fexp2(1.4426950408889634f * (l0 - m));
  const float e1 = fexp2(1.4426950408889634f * (l1 - m));
  const float inv = frcp(e0 + e1);
  reinterpret_cast<float2*>(out)[b] = make_float2(e0 * inv, e1 * inv);
}

extern "C" void kernel_launch(void* const* d_in, const int* in_sizes, int n_in,
                              void* d_out, int out_size, void* d_ws, size_t ws_size,
                              hipStream_t stream) {
  (void)in_sizes; (void)n_in; (void)out_size; (void)ws_size;
  const float* q = (const float*)d_in[0];
  const float* p = (const float*)d_in[1];
  float* ws = (float*)d_ws;

  lstm_towers<<<NBLK, 512, 0, stream>>>(
      q, p,
      (const float*)d_in[2], (const float*)d_in[3], (const float*)d_in[4],
      (const float*)d_in[5], (const float*)d_in[6], (const float*)d_in[7],
      (const float*)d_in[8], (const float*)d_in[9], (const float*)d_in[10],
      (const float*)d_in[11], (const float*)d_in[12], (const float*)d_in[13],
      (const float*)d_in[14], (const float*)d_in[15], (const float*)d_in[16],
      (const float*)d_in[17], (const float*)d_in[18], (const float*)d_in[19],
      ws + HQ_OFF, ws + HP_OFF);

  combine_head<<<B_TOTAL / 256, 256, 0, stream>>>(
      ws + HQ_OFF, ws + HP_OFF,
      (const float*)d_in[20], (const float*)d_in[21], (float*)d_out);
}